// Round 9
// baseline (770.831 us; speedup 1.0000x reference)
//
#include <hip/hip_runtime.h>
#include <hip/hip_bf16.h>
#include <math.h>

typedef __bf16 bf16;
typedef bf16 bf16x8 __attribute__((ext_vector_type(8)));
typedef float f32x4 __attribute__((ext_vector_type(4)));

#define LDS16(gp, lp) __builtin_amdgcn_global_load_lds( \
    (const __attribute__((address_space(1))) unsigned int*)(gp), \
    (__attribute__((address_space(3))) unsigned int*)(lp), 16, 0, 0)

// cumulative chunk offset for q-pair tile qtp (128 q rows; chunks of 8 key-tiles)
__device__ __forceinline__ int cumoff2(int qtp) {
  if (qtp < 4)  return qtp;
  if (qtp < 8)  return 4 + 2 * (qtp - 4);
  if (qtp < 12) return 12 + 3 * (qtp - 8);
  return 24 + 4 * (qtp - 12);
}

// ---------------------------------------------------------------------------
// Weight convert + transpose: W fp32 [K][N] -> WT bf16 [Np][Kp], zero padded.
// blockIdx.z = layer.
// ---------------------------------------------------------------------------
__global__ void convert_w_kernel(const float* __restrict__ W, bf16* __restrict__ WT,
                                 int K, int N, int Kp, int Np,
                                 size_t wstride, size_t wtstride)
{
  __shared__ float tile[32][33];
  const float* Wl = W + blockIdx.z * wstride;
  bf16* WTl = WT + blockIdx.z * wtstride;
  int k0 = blockIdx.x * 32, n0 = blockIdx.y * 32;
  int tx = threadIdx.x, ty = threadIdx.y;
  for (int i = ty; i < 32; i += 8) {
    int k = k0 + i, n = n0 + tx;
    tile[i][tx] = (k < K && n < N) ? Wl[(size_t)k * N + n] : 0.f;
  }
  __syncthreads();
  for (int i = ty; i < 32; i += 8) {
    int n = n0 + i, k = k0 + tx;
    if (n < Np && k < Kp) WTl[(size_t)n * Kp + k] = (bf16)tile[tx][i];
  }
}

// ---------------------------------------------------------------------------
// ff_in convert with a/g interleave: out-row 2i <- W col i (a), 2i+1 <- col
// 1365+i (g). W fp32 [512][2730] -> WT bf16 [2816][512]. blockIdx.z = layer.
// ---------------------------------------------------------------------------
__global__ void convert_w_ffin_kernel(const float* __restrict__ W, bf16* __restrict__ WT)
{
  __shared__ float tile[32][33];
  const float* Wl = W + (size_t)blockIdx.z * 512 * 2730;
  bf16* WTl = WT + (size_t)blockIdx.z * 2816 * 512;
  int k0 = blockIdx.x * 32, n0 = blockIdx.y * 32;
  int tx = threadIdx.x, ty = threadIdx.y;
  for (int i = ty; i < 32; i += 8) {
    int k = k0 + i, n = n0 + tx;
    int pair = n >> 1;
    int col = (n & 1) ? 1365 + pair : pair;
    tile[i][tx] = (pair < 1365) ? Wl[(size_t)k * 2730 + col] : 0.f;
  }
  __syncthreads();
  for (int i = ty; i < 32; i += 8) {
    int n = n0 + i, k = k0 + tx;
    WTl[(size_t)n * 512 + k] = (bf16)tile[tx][i];
  }
}

// interleaved ff_in bias: ib[l][n] = ffib[l][ (n&1)?1365+(n>>1):(n>>1) ], pad 0.
__global__ __launch_bounds__(256)
void ibias_kernel(const float* __restrict__ ffib, float* __restrict__ ib)
{
  int idx = blockIdx.x * 256 + threadIdx.x;   // 4*2816
  int l = idx / 2816, n = idx - l * 2816;
  int pair = n >> 1;
  int col = (n & 1) ? 1365 + pair : pair;
  ib[idx] = (pair < 1365) ? ffib[l * 2730 + col] : 0.f;
}

// ---------------------------------------------------------------------------
// RoPE table: cos/sin for (s in [0,2048), j in [0,32)).
// ---------------------------------------------------------------------------
__global__ __launch_bounds__(256)
void rope_kernel(float* __restrict__ tab)
{
  int idx = blockIdx.x * 256 + threadIdx.x;
  int s = idx >> 5, j = idx & 31;
  float invf = (float)exp((double)(2 * j) * -0.14391156847064293);
  float ang = (float)s * invf;
  float sn, cs;
  sincosf(ang, &sn, &cs);
  tab[idx] = cs;
  tab[65536 + idx] = sn;
}

// ---------------------------------------------------------------------------
// RMSNorm over rows of 512 fp32. One wave per row, 4 rows per block.
// ---------------------------------------------------------------------------
template<bool BF16OUT>
__global__ __launch_bounds__(256)
void rmsnorm_kernel(const float* __restrict__ in, const float* __restrict__ wgt,
                    void* __restrict__ outp)
{
  int row = blockIdx.x * 4 + (threadIdx.x >> 6);
  int lane = threadIdx.x & 63;
  const float* p = in + (size_t)row * 512;
  float4 v0 = *(const float4*)(p + lane * 4);
  float4 v1 = *(const float4*)(p + 256 + lane * 4);
  float ss = v0.x*v0.x + v0.y*v0.y + v0.z*v0.z + v0.w*v0.w
           + v1.x*v1.x + v1.y*v1.y + v1.z*v1.z + v1.w*v1.w;
  #pragma unroll
  for (int d = 1; d < 64; d <<= 1) ss += __shfl_xor(ss, d);
  float sc = rsqrtf(ss * (1.f / 512.f) + 1.1920929e-7f);
  float a0[4] = {v0.x, v0.y, v0.z, v0.w};
  float a1[4] = {v1.x, v1.y, v1.z, v1.w};
  #pragma unroll
  for (int i = 0; i < 4; ++i) {
    int c0 = lane * 4 + i, c1 = 256 + lane * 4 + i;
    float r0 = a0[i] * sc * wgt[c0];
    float r1 = a1[i] * sc * wgt[c1];
    if (BF16OUT) {
      ((bf16*)outp)[(size_t)row * 512 + c0] = (bf16)r0;
      ((bf16*)outp)[(size_t)row * 512 + c1] = (bf16)r1;
    } else {
      ((float*)outp)[(size_t)row * 512 + c0] = r0;
      ((float*)outp)[(size_t)row * 512 + c1] = r1;
    }
  }
}

// ---------------------------------------------------------------------------
// qkv post with LDS transpose for vT. grid (st=32, bh=16), 256 threads.
// Phase 1: thread (sl,dg) handles row s=st*64+sl, d=dg*16..+15: coalesced
// loads, rope q/k -> coalesced stores, v-mix -> fp32 LDS tile [s][d].
// Phase 2: thread (d,q4) reads LDS column-wise, writes vT[d][s] coalesced.
// LDS stride 65 words: both phases max 2-way bank aliasing (free).
// ---------------------------------------------------------------------------
__global__ __launch_bounds__(256, 4)
void qkvpost_kernel(const bf16* __restrict__ qkv, const float* __restrict__ mb,
                    const float* __restrict__ rope, bf16* __restrict__ firstv,
                    bf16* __restrict__ qb, bf16* __restrict__ kb,
                    bf16* __restrict__ vT, int layer)
{
  __shared__ float smv[64][65];
  const int st = blockIdx.x, bh = blockIdx.y;
  const int b = bh >> 3, h = bh & 7;
  const int tid = threadIdx.x;
  const int sl = tid >> 2, dg = tid & 3;
  const int s = st * 64 + sl;
  const size_t row = (size_t)b * 2048 + s;
  const bf16* base = qkv + row * 1664 + h * 64 + dg * 16;

  bf16x8 qv0 = *(const bf16x8*)(base);
  bf16x8 qv1 = *(const bf16x8*)(base + 8);
  bf16x8 kv0 = *(const bf16x8*)(base + 512);
  bf16x8 kv1 = *(const bf16x8*)(base + 520);
  bf16x8 vv0 = *(const bf16x8*)(base + 1024);
  bf16x8 vv1 = *(const bf16x8*)(base + 1032);

  float cs8[8], sn8[8];
  #pragma unroll
  for (int j = 0; j < 8; ++j) {
    cs8[j] = rope[s * 32 + dg * 8 + j];
    sn8[j] = rope[65536 + s * 32 + dg * 8 + j];
  }

  const size_t qoff = ((size_t)bh * 2048 + s) * 64 + dg * 16;
  bf16x8 oq0, oq1, ok0, ok1;
  #pragma unroll
  for (int p = 0; p < 4; ++p) {
    float q1 = (float)qv0[2 * p], q2 = (float)qv0[2 * p + 1];
    float k1 = (float)kv0[2 * p], k2 = (float)kv0[2 * p + 1];
    oq0[2 * p]     = (bf16)((q1 * cs8[p] - q2 * sn8[p]) * 0.125f);
    oq0[2 * p + 1] = (bf16)((q1 * sn8[p] + q2 * cs8[p]) * 0.125f);
    ok0[2 * p]     = (bf16)(k1 * cs8[p] - k2 * sn8[p]);
    ok0[2 * p + 1] = (bf16)(k1 * sn8[p] + k2 * cs8[p]);
    float q3 = (float)qv1[2 * p], q4v = (float)qv1[2 * p + 1];
    float k3 = (float)kv1[2 * p], k4 = (float)kv1[2 * p + 1];
    oq1[2 * p]     = (bf16)((q3 * cs8[p + 4] - q4v * sn8[p + 4]) * 0.125f);
    oq1[2 * p + 1] = (bf16)((q3 * sn8[p + 4] + q4v * cs8[p + 4]) * 0.125f);
    ok1[2 * p]     = (bf16)(k3 * cs8[p + 4] - k4 * sn8[p + 4]);
    ok1[2 * p + 1] = (bf16)(k3 * sn8[p + 4] + k4 * cs8[p + 4]);
  }
  *(bf16x8*)(qb + qoff)     = oq0;
  *(bf16x8*)(qb + qoff + 8) = oq1;
  *(bf16x8*)(kb + qoff)     = ok0;
  *(bf16x8*)(kb + qoff + 8) = ok1;

  float vout[16];
  #pragma unroll
  for (int i = 0; i < 8; ++i) { vout[i] = (float)vv0[i]; vout[8 + i] = (float)vv1[i]; }
  if (layer == 0) {
    *(bf16x8*)(firstv + qoff)     = vv0;
    *(bf16x8*)(firstv + qoff + 8) = vv1;
  } else {
    float logit = (float)qkv[row * 1664 + 1536 + h] + mb[h];
    float mx = 1.f / (1.f + __expf(-logit));
    bf16x8 fv0 = *(const bf16x8*)(firstv + qoff);
    bf16x8 fv1 = *(const bf16x8*)(firstv + qoff + 8);
    #pragma unroll
    for (int i = 0; i < 8; ++i) {
      vout[i]     += mx * ((float)fv0[i] - vout[i]);
      vout[8 + i] += mx * ((float)fv1[i] - vout[8 + i]);
    }
  }
  #pragma unroll
  for (int i = 0; i < 16; ++i)
    smv[sl][dg * 16 + i] = vout[i];

  __syncthreads();

  const int d = tid >> 2, q4 = tid & 3;
  bf16x8 o0, o1;
  #pragma unroll
  for (int i = 0; i < 8; ++i) {
    o0[i] = (bf16)smv[q4 * 16 + i][d];
    o1[i] = (bf16)smv[q4 * 16 + 8 + i][d];
  }
  bf16* vp = vT + ((size_t)bh * 64 + d) * 2048 + st * 64 + q4 * 16;
  *(bf16x8*)(vp)     = o0;
  *(bf16x8*)(vp + 8) = o1;
}

// ---------------------------------------------------------------------------
// Split-K flash attention, 128 q-rows/block, block-causal (block 32).
// 640 blocks, 256 threads. Fixed-max softmax; bf16 O-partials.
// Triple-buffered K/V ring, prefetch distance 2: barriers use raw s_barrier
// with s_waitcnt vmcnt(4) so the newest prefetch (4 LDS16/wave) stays in
// flight across the barrier (AITER-style). Each wave drains ITS OWN tile-j
// loads before signaling, so all waves' staging is LDS-visible after barrier.
// ---------------------------------------------------------------------------
__global__ __launch_bounds__(256, 2)
void attn_kernel(const bf16* __restrict__ Q, const bf16* __restrict__ Kmat,
                 const bf16* __restrict__ VT, bf16* __restrict__ Opart,
                 float* __restrict__ lbuf)
{
  __shared__ __align__(16) bf16 smK[3][8 * 512];   // [buf][(nt*2+ks)*512]
  __shared__ __align__(16) bf16 smV[3][8 * 512];
  __shared__ __align__(16) bf16 smP[4][2][16 * 72];
  const int bid = blockIdx.x;
  const int bh = bid & 15;
  const int cidx = bid >> 4;          // [0,40)
  int qtp, chunk;
  if (cidx < 4)       { qtp = cidx; chunk = 0; }
  else if (cidx < 12) { qtp = 4 + ((cidx - 4) >> 1);  chunk = (cidx - 4) & 1; }
  else if (cidx < 24) { int t = cidx - 12; qtp = 8 + t / 3; chunk = t - (qtp - 8) * 3; }
  else                { int t = cidx - 24; qtp = 12 + (t >> 2); chunk = t & 3; }
  const int jt0 = chunk * 8;
  const int njt = min(jt0 + 8, 2 * qtp + 2) - jt0;

  const int tid = threadIdx.x;
  const int w = tid >> 6, lane = tid & 63;
  const int c = lane & 15, quad = lane >> 4;
  const int jtmax_w = (qtp * 4 + w) >> 1;   // last key-tile this wave can see

  const size_t qrow0 = (size_t)bh * 2048 + qtp * 128 + w * 32;
  bf16x8 aQ[2][2];
  #pragma unroll
  for (int m = 0; m < 2; ++m) {
    aQ[m][0] = *(const bf16x8*)(Q + (qrow0 + m * 16 + c) * 64 + quad * 8);
    aQ[m][1] = *(const bf16x8*)(Q + (qrow0 + m * 16 + c) * 64 + 32 + quad * 8);
  }

  const bf16* Kg = Kmat + ((size_t)bh * 2048 + w * 16 + c) * 64 + quad * 8;
  const bf16* Vg = VT + ((size_t)bh * 64 + w * 16 + c) * 2048 + quad * 8;

  auto stage = [&](int tile, int buf) {
    const bf16* kp = Kg + (size_t)tile * 4096;
    const bf16* vp = Vg + tile * 64;
    bf16* kd = smK[buf] + w * 1024;
    bf16* vd = smV[buf] + w * 1024;
    LDS16(kp,      kd);
    LDS16(kp + 32, kd + 512);
    LDS16(vp,      vd);
    LDS16(vp + 32, vd + 512);
  };
  stage(jt0, 0);
  if (njt > 1) stage(jt0 + 1, 1);

  f32x4 o[2][4] = {};
  float lacc[2][4] = {};

  for (int j = 0; j < njt; ++j) {
    const int bufc = j % 3;
    const int jt = jt0 + j;
    // barrier: own tile-j loads must be done (4 newest = tile j+1 may fly)
    if (j + 1 < njt) asm volatile("s_waitcnt vmcnt(4)\n\ts_barrier" ::: "memory");
    else             asm volatile("s_waitcnt vmcnt(0)\n\ts_barrier" ::: "memory");
    if (j + 2 < njt) stage(jt0 + j + 2, (j + 2) % 3);
    if (jt > jtmax_w) continue;

    f32x4 s[2][4];
    #pragma unroll
    for (int nt = 0; nt < 4; ++nt) {
      bf16x8 bK0 = *(const bf16x8*)(smK[bufc] + (nt * 2) * 512 + lane * 8);
      bf16x8 bK1 = *(const bf16x8*)(smK[bufc] + (nt * 2 + 1) * 512 + lane * 8);
      #pragma unroll
      for (int m = 0; m < 2; ++m) {
        f32x4 acc = {0.f, 0.f, 0.f, 0.f};
        acc = __builtin_amdgcn_mfma_f32_16x16x32_bf16(aQ[m][0], bK0, acc, 0, 0, 0);
        acc = __builtin_amdgcn_mfma_f32_16x16x32_bf16(aQ[m][1], bK1, acc, 0, 0, 0);
        s[m][nt] = acc;
      }
    }
    if (2 * jt + 1 > 4 * qtp + w) {
      #pragma unroll
      for (int m = 0; m < 2; ++m)
        #pragma unroll
        for (int r = 0; r < 4; ++r) { s[m][2][r] = -3.0e38f; s[m][3][r] = -3.0e38f; }
    }

    #pragma unroll
    for (int m = 0; m < 2; ++m) {
      #pragma unroll
      for (int r = 0; r < 4; ++r) {
        float p0 = __expf(s[m][0][r]);
        float p1 = __expf(s[m][1][r]);
        float p2 = __expf(s[m][2][r]);
        float p3 = __expf(s[m][3][r]);
        lacc[m][r] += (p0 + p1) + (p2 + p3);
        bf16* pp = smP[w][m] + (quad * 4 + r) * 72 + c;
        pp[0]  = (bf16)p0;
        pp[16] = (bf16)p1;
        pp[32] = (bf16)p2;
        pp[48] = (bf16)p3;
      }
    }
    asm volatile("s_waitcnt lgkmcnt(0)" ::: "memory");

    #pragma unroll
    for (int ks2 = 0; ks2 < 2; ++ks2) {
      #pragma unroll
      for (int m = 0; m < 2; ++m) {
        bf16x8 aP = *(const bf16x8*)(smP[w][m] + c * 72 + ks2 * 32 + quad * 8);
        #pragma unroll
        for (int nt = 0; nt < 4; ++nt) {
          bf16x8 bV = *(const bf16x8*)(smV[bufc] + (nt * 2 + ks2) * 512 + lane * 8);
          o[m][nt] = __builtin_amdgcn_mfma_f32_16x16x32_bf16(aP, bV, o[m][nt], 0, 0, 0);
        }
      }
    }
  }

  #pragma unroll
  for (int m = 0; m < 2; ++m)
    #pragma unroll
    for (int r = 0; r < 4; ++r) {
      float v = lacc[m][r];
      #pragma unroll
      for (int d = 1; d < 16; d <<= 1) v += __shfl_xor(v, d);
      lacc[m][r] = v;
    }

  const int slot = bh * 40 + cumoff2(qtp) + chunk;
  bf16* Op = Opart + (size_t)slot * 8192;
  #pragma unroll
  for (int m = 0; m < 2; ++m) {
    #pragma unroll
    for (int r = 0; r < 4; ++r) {
      int prow = w * 32 + m * 16 + quad * 4 + r;
      #pragma unroll
      for (int nt = 0; nt < 4; ++nt)
        Op[prow * 64 + nt * 16 + c] = (bf16)o[m][nt][r];
      if (c == 0) lbuf[slot * 128 + prow] = lacc[m][r];
    }
  }
}

// ---------------------------------------------------------------------------
// Combine split-K partials (bf16) -> bf16 O [b][s][512]. grid (32,16), 256 thr.
// ---------------------------------------------------------------------------
__global__ __launch_bounds__(256)
void attn_combine_kernel(const bf16* __restrict__ Opart, const float* __restrict__ lbuf,
                         bf16* __restrict__ Omat)
{
  const int qt = blockIdx.x, bh = blockIdx.y;
  const int qtp = qt >> 1;
  const int nch = (2 * qtp + 9) >> 3;           // ceil((2*qtp+2)/8)
  const int base = bh * 40 + cumoff2(qtp);
  const int tid = threadIdx.x;
  const int row = tid >> 2, cg = tid & 3;
  const int prow = (qt & 1) * 64 + row;

  float L = 0.f;
  float acc[16] = {};
  #pragma unroll
  for (int ch = 0; ch < 4; ++ch) {
    if (ch < nch) {
      L += lbuf[(base + ch) * 128 + prow];
      const bf16* p = Opart + (size_t)(base + ch) * 8192 + prow * 64 + cg * 16;
      bf16x8 u0 = *(const bf16x8*)(p);
      bf16x8 u1 = *(const bf16x8*)(p + 8);
      #pragma unroll
      for (int i = 0; i < 8; ++i) { acc[i] += (float)u0[i]; acc[8 + i] += (float)u1[i]; }
    }
  }
  float inv = 1.f / L;

  const int b = bh >> 3, h = bh & 7;
  bf16* op = Omat + ((size_t)b * 2048 + qt * 64 + row) * 512 + h * 64 + cg * 16;
  #pragma unroll
  for (int i = 0; i < 16; ++i)
    op[i] = (bf16)(acc[i] * inv);
}

// ---------------------------------------------------------------------------
// GEMM 128x128: C[M][N] = A[M][K](bf16) @ WT[N][K](bf16)^T
// MODE 0: bf16 out (+bias). MODE 2: fp32 out = Tin + acc + bias.
// MODE 3: gated-gelu epilogue (interleaved a/g cols): out bf16 [M][N/2].
// ---------------------------------------------------------------------------
template<int MODE>
__global__ __launch_bounds__(256, 2)
void gemm_kernel(const bf16* __restrict__ A, const bf16* __restrict__ WT,
                 const float* __restrict__ bias, int n_bias,
                 const float* __restrict__ Tin, void* __restrict__ outp,
                 int K, int N)
{
  __shared__ __align__(16) bf16 smA[8 * 512];
  __shared__ __align__(16) bf16 smB[8 * 512];
  const int tid = threadIdx.x;
  const int w = tid >> 6, lane = tid & 63;
  const int c = lane & 15, quad = lane >> 4;
  const int wy = w >> 1, wx = w & 1;
  const int bm = blockIdx.y * 128, bn = blockIdx.x * 128;

  f32x4 acc[4][4] = {};

  const bf16* Ag0 = A  + (size_t)(bm + (w * 2)     * 16 + c) * K + quad * 8;
  const bf16* Ag1 = A  + (size_t)(bm + (w * 2 + 1) * 16 + c) * K + quad * 8;
  const bf16* Bg0 = WT + (size_t)(bn + (w * 2)     * 16 + c) * K + quad * 8;
  const bf16* Bg1 = WT + (size_t)(bn + (w * 2 + 1) * 16 + c) * K + quad * 8;
  bf16* la0 = smA + (w * 2) * 512;
  bf16* la1 = smA + (w * 2 + 1) * 512;
  bf16* lb0 = smB + (w * 2) * 512;
  bf16* lb1 = smB + (w * 2 + 1) * 512;

  const int NK = K >> 5;
  for (int kk = 0; kk < NK; ++kk) {
    const int ko = kk * 32;
    LDS16(Ag0 + ko, la0);
    LDS16(Ag1 + ko, la1);
    LDS16(Bg0 + ko, lb0);
    LDS16(Bg1 + ko, lb1);
    __syncthreads();
    bf16x8 af[4], bfr[4];
    #pragma unroll
    for (int mt = 0; mt < 4; ++mt)
      af[mt] = *(const bf16x8*)(smA + (wy * 4 + mt) * 512 + lane * 8);
    #pragma unroll
    for (int nt = 0; nt < 4; ++nt)
      bfr[nt] = *(const bf16x8*)(smB + (wx * 4 + nt) * 512 + lane * 8);
    #pragma unroll
    for (int mt = 0; mt < 4; ++mt)
      #pragma unroll
      for (int nt = 0; nt < 4; ++nt)
        acc[mt][nt] = __builtin_amdgcn_mfma_f32_16x16x32_bf16(af[mt], bfr[nt], acc[mt][nt], 0, 0, 0);
    __syncthreads();
  }

  const int r0 = bm + wy * 64;
  const int c0 = bn + wx * 64;
  #pragma unroll
  for (int mt = 0; mt < 4; ++mt) {
    #pragma unroll
    for (int nt = 0; nt < 4; ++nt) {
      #pragma unroll
      for (int r = 0; r < 4; ++r) {
        size_t row = (size_t)(r0 + mt * 16 + quad * 4 + r);
        int col = c0 + nt * 16 + c;
        float v = acc[mt][nt][r];
        if (MODE == 3) {
          v += bias[col];
          float g = __shfl_xor(v, 1);
          if ((c & 1) == 0) {
            float outv = v * 0.5f * g * (1.f + erff(g * 0.70710678118654752f));
            ((bf16*)outp)[row * (size_t)(N >> 1) + (col >> 1)] = (bf16)outv;
          }
        } else {
          float bv = (bias != nullptr && col < n_bias) ? bias[col] : 0.f;
          if (MODE == 2) {
            ((float*)outp)[row * N + col] = Tin[row * N + col] + v + bv;
          } else {
            ((bf16*)outp)[row * N + col] = (bf16)(v + bv);
          }
        }
      }
    }
  }
}

// ---------------------------------------------------------------------------
// GEMM 64x64 (for N=512 GEMMs: 4x the blocks of the 128-tile version).
// ---------------------------------------------------------------------------
template<int MODE>
__global__ __launch_bounds__(256, 4)
void gemm64_kernel(const bf16* __restrict__ A, const bf16* __restrict__ WT,
                   const float* __restrict__ bias, int n_bias,
                   const float* __restrict__ Tin, void* __restrict__ outp,
                   int K, int N)
{
  __shared__ __align__(16) bf16 smA[4 * 512];
  __shared__ __align__(16) bf16 smB[4 * 512];
  const int tid = threadIdx.x;
  const int w = tid >> 6, lane = tid & 63;
  const int c = lane & 15, quad = lane >> 4;
  const int wy = w >> 1, wx = w & 1;
  const int bm = blockIdx.y * 64, bn = blockIdx.x * 64;

  f32x4 acc[2][2] = {};

  const bf16* Ag = A  + (size_t)(bm + w * 16 + c) * K + quad * 8;
  const bf16* Bg = WT + (size_t)(bn + w * 16 + c) * K + quad * 8;
  bf16* la = smA + w * 512;
  bf16* lb = smB + w * 512;

  const int NK = K >> 5;
  for (int kk = 0; kk < NK; ++kk) {
    const int ko = kk * 32;
    LDS16(Ag + ko, la);
    LDS16(Bg + ko, lb);
    __syncthreads();
    bf16x8 af[2], bfr[2];
    #pragma unroll
    for (int mt = 0; mt < 2; ++mt)
      af[mt] = *(const bf16x8*)(smA + (wy * 2 + mt) * 512 + lane * 8);
    #pragma unroll
    for (int nt = 0; nt < 2; ++nt)
      bfr[nt] = *(const bf16x8*)(smB + (wx * 2 + nt) * 512 + lane * 8);
    #pragma unroll
    for (int mt = 0; mt < 2; ++mt)
      #pragma unroll
      for (int nt = 0; nt < 2; ++nt)
        acc[mt][nt] = __builtin_amdgcn_mfma_f32_16x16x32_bf16(af[mt], bfr[nt], acc[mt][nt], 0, 0, 0);
    __syncthreads();
  }

  const int r0 = bm + wy * 32;
  const int c0 = bn + wx * 32;
  #pragma unroll
  for (int mt = 0; mt < 2; ++mt) {
    #pragma unroll
    for (int nt = 0; nt < 2; ++nt) {
      #pragma unroll
      for (int r = 0; r < 4; ++r) {
        size_t row = (size_t)(r0 + mt * 16 + quad * 4 + r);
        int col = c0 + nt * 16 + c;
        float v = acc[mt][nt][r];
        float bv = (bias != nullptr && col < n_bias) ? bias[col] : 0.f;
        if (MODE == 2) {
          ((float*)outp)[row * N + col] = Tin[row * N + col] + v + bv;
        } else {
          ((bf16*)outp)[row * N + col] = (bf16)(v + bv);
        }
      }
    }
  }
}

// ---------------------------------------------------------------------------
extern "C" void kernel_launch(void* const* d_in, const int* in_sizes, int n_in,
                              void* d_out, int out_size, void* d_ws, size_t ws_size,
                              hipStream_t stream)
{
  const float* tokens  = (const float*)d_in[0];
  const float* anw     = (const float*)d_in[1];
  const float* qkvw    = (const float*)d_in[2];
  const float* outw    = (const float*)d_in[3];
  const float* mixw    = (const float*)d_in[4];
  const float* mixbias = (const float*)d_in[5];
  const float* fnw     = (const float*)d_in[6];
  const float* ffiw    = (const float*)d_in[7];
  const float* ffib    = (const float*)d_in[8];
  const float* ffow    = (const float*)d_in[9];
  const float* ffob    = (const float*)d_in[10];
  const float* finw    = (const float*)d_in[11];
  float* outp = (float*)d_out;

  char* ws = (char*)d_ws;
  size_t off = 0;
  auto alloc = [&](size_t bytes) -> char* {
    char* p = ws + off;
    off += (bytes + 255) & ~(size_t)255;
    return p;
  };
  bf16* wtq    = (bf16*)alloc((size_t)4 * 1664 * 512 * 2);   // qkv + mix(8, pad 128)
  bf16* wto    = (bf16*)alloc((size_t)4 * 512 * 512 * 2);
  bf16* wtfi   = (bf16*)alloc((size_t)4 * 2816 * 512 * 2);   // interleaved a/g
  bf16* wtfo   = (bf16*)alloc((size_t)4 * 512 * 1408 * 2);
  float* ibias = (float*)alloc((size_t)4 * 2816 * 4);
  float* tbuf  = (float*)alloc((size_t)4096 * 512 * 4);
  bf16* xb     = (bf16*)alloc((size_t)4096 * 512 * 2);
  bf16* yb     = (bf16*)alloc((size_t)4096 * 512 * 2);
  char* qkvraw = alloc((size_t)4096 * 1664 * 2);           // bf16 qkv / bf16 Opart alias
  bf16* fv     = (bf16*)alloc((size_t)16 * 2048 * 64 * 2);
  bf16* qb     = (bf16*)alloc((size_t)16 * 2048 * 64 * 2);
  bf16* kbuf   = (bf16*)alloc((size_t)16 * 2048 * 64 * 2);
  bf16* vT     = (bf16*)alloc((size_t)16 * 2048 * 64 * 2);
  bf16* ob     = (bf16*)alloc((size_t)4096 * 512 * 2);
  bf16* actb   = (bf16*)alloc((size_t)4096 * 1408 * 2);
  float* rope  = (float*)alloc((size_t)2 * 65536 * 4);
  float* lbuf  = (float*)alloc((size_t)640 * 128 * 4);
  bf16* qkvbf  = (bf16*)qkvraw;
  bf16* Opart  = (bf16*)qkvraw;   // 10.5 MB <= 13.6 MB; qkv dead after qkvpost

  dim3 tcv(32, 8);
  convert_w_kernel<<<dim3(16, 48, 4), tcv, 0, stream>>>(
      qkvw, wtq, 512, 1536, 512, 1536, (size_t)512 * 1536, (size_t)1664 * 512);
  convert_w_kernel<<<dim3(16, 4, 4), tcv, 0, stream>>>(
      mixw, wtq + (size_t)1536 * 512, 512, 8, 512, 128, (size_t)512 * 8, (size_t)1664 * 512);
  convert_w_kernel<<<dim3(16, 16, 4), tcv, 0, stream>>>(
      outw, wto, 512, 512, 512, 512, (size_t)512 * 512, (size_t)512 * 512);
  convert_w_ffin_kernel<<<dim3(16, 88, 4), tcv, 0, stream>>>(ffiw, wtfi);
  convert_w_kernel<<<dim3(44, 16, 4), tcv, 0, stream>>>(
      ffow, wtfo, 1365, 512, 1408, 512, (size_t)1365 * 512, (size_t)1408 * 512);
  ibias_kernel<<<44, 256, 0, stream>>>(ffib, ibias);
  rope_kernel<<<256, 256, 0, stream>>>(rope);
  hipMemcpyAsync(tbuf, tokens, (size_t)4096 * 512 * 4, hipMemcpyDeviceToDevice, stream);

  for (int l = 0; l < 4; ++l) {
    rmsnorm_kernel<true><<<1024, 256, 0, stream>>>(tbuf, anw + l * 512, xb);
    gemm_kernel<0><<<dim3(13, 32), 256, 0, stream>>>(
        xb, wtq + (size_t)l * 1664 * 512, nullptr, 0, nullptr, qkvbf, 512, 1664);
    qkvpost_kernel<<<dim3(32, 16), 256, 0, stream>>>(qkvbf, mixbias + l * 8, rope, fv, qb, kbuf, vT, l);
    attn_kernel<<<640, 256, 0, stream>>>(qb, kbuf, vT, Opart, lbuf);
    attn_combine_kernel<<<dim3(32, 16), 256, 0, stream>>>(Opart, lbuf, ob);
    gemm64_kernel<2><<<dim3(8, 64), 256, 0, stream>>>(
        ob, wto + (size_t)l * 512 * 512, nullptr, 0, tbuf, tbuf, 512, 512);
    rmsnorm_kernel<true><<<1024, 256, 0, stream>>>(tbuf, fnw + l * 512, yb);
    gemm_kernel<3><<<dim3(22, 32), 256, 0, stream>>>(
        yb, wtfi + (size_t)l * 2816 * 512, ibias + (size_t)l * 2816, 2816, nullptr, actb, 512, 2816);
    gemm64_kernel<2><<<dim3(8, 64), 256, 0, stream>>>(
        actb, wtfo + (size_t)l * 512 * 1408, ffob + (size_t)l * 512, 512, tbuf, tbuf, 1408, 512);
  }
  rmsnorm_kernel<false><<<1024, 256, 0, stream>>>(tbuf, finw, outp);
}

// Round 10
// 717.088 us; speedup vs baseline: 1.0749x; 1.0749x over previous
//
#include <hip/hip_runtime.h>
#include <hip/hip_bf16.h>
#include <math.h>

typedef __bf16 bf16;
typedef bf16 bf16x8 __attribute__((ext_vector_type(8)));
typedef float f32x4 __attribute__((ext_vector_type(4)));

#define LDS16(gp, lp) __builtin_amdgcn_global_load_lds( \
    (const __attribute__((address_space(1))) unsigned int*)(gp), \
    (__attribute__((address_space(3))) unsigned int*)(lp), 16, 0, 0)

// cumulative chunk offset for q-pair tile qtp (128 q rows; chunks of 8 key-tiles)
__device__ __forceinline__ int cumoff2(int qtp) {
  if (qtp < 4)  return qtp;
  if (qtp < 8)  return 4 + 2 * (qtp - 4);
  if (qtp < 12) return 12 + 3 * (qtp - 8);
  return 24 + 4 * (qtp - 12);
}

// ---------------------------------------------------------------------------
// Weight convert + transpose: W fp32 [K][N] -> WT bf16 [Np][Kp], zero padded.
// Optional per-k scale (rmsnorm weight fold): W'[k][n] = ks[z*K+k]*W[k][n].
// blockIdx.z = layer.
// ---------------------------------------------------------------------------
__global__ void convert_w_kernel(const float* __restrict__ W, bf16* __restrict__ WT,
                                 const float* __restrict__ ks,
                                 int K, int N, int Kp, int Np,
                                 size_t wstride, size_t wtstride)
{
  __shared__ float tile[32][33];
  const float* Wl = W + blockIdx.z * wstride;
  bf16* WTl = WT + blockIdx.z * wtstride;
  int k0 = blockIdx.x * 32, n0 = blockIdx.y * 32;
  int tx = threadIdx.x, ty = threadIdx.y;
  for (int i = ty; i < 32; i += 8) {
    int k = k0 + i, n = n0 + tx;
    float v = (k < K && n < N) ? Wl[(size_t)k * N + n] : 0.f;
    if (ks && k < K) v *= ks[blockIdx.z * K + k];
    tile[i][tx] = v;
  }
  __syncthreads();
  for (int i = ty; i < 32; i += 8) {
    int n = n0 + i, k = k0 + tx;
    if (n < Np && k < Kp) WTl[(size_t)n * Kp + k] = (bf16)tile[tx][i];
  }
}

// ---------------------------------------------------------------------------
// ff_in convert with a/g interleave + ff_norm fold: out-row 2i <- col i (a),
// 2i+1 <- col 1365+i (g). W fp32 [512][2730] -> WT bf16 [2816][512].
// ---------------------------------------------------------------------------
__global__ void convert_w_ffin_kernel(const float* __restrict__ W, bf16* __restrict__ WT,
                                      const float* __restrict__ fnw)
{
  __shared__ float tile[32][33];
  const float* Wl = W + (size_t)blockIdx.z * 512 * 2730;
  bf16* WTl = WT + (size_t)blockIdx.z * 2816 * 512;
  int k0 = blockIdx.x * 32, n0 = blockIdx.y * 32;
  int tx = threadIdx.x, ty = threadIdx.y;
  for (int i = ty; i < 32; i += 8) {
    int k = k0 + i, n = n0 + tx;
    int pair = n >> 1;
    int col = (n & 1) ? 1365 + pair : pair;
    float v = (pair < 1365) ? Wl[(size_t)k * 2730 + col] : 0.f;
    tile[i][tx] = v * fnw[blockIdx.z * 512 + k];
  }
  __syncthreads();
  for (int i = ty; i < 32; i += 8) {
    int n = n0 + i, k = k0 + tx;
    WTl[(size_t)n * 512 + k] = (bf16)tile[tx][i];
  }
}

// interleaved ff_in bias: ib[l][n] = ffib[l][ (n&1)?1365+(n>>1):(n>>1) ], pad 0.
__global__ __launch_bounds__(256)
void ibias_kernel(const float* __restrict__ ffib, float* __restrict__ ib)
{
  int idx = blockIdx.x * 256 + threadIdx.x;   // 4*2816
  int l = idx / 2816, n = idx - l * 2816;
  int pair = n >> 1;
  int col = (n & 1) ? 1365 + pair : pair;
  ib[idx] = (pair < 1365) ? ffib[l * 2730 + col] : 0.f;
}

// ---------------------------------------------------------------------------
// RoPE table: cos/sin for (s in [0,2048), j in [0,32)).
// ---------------------------------------------------------------------------
__global__ __launch_bounds__(256)
void rope_kernel(float* __restrict__ tab)
{
  int idx = blockIdx.x * 256 + threadIdx.x;
  int s = idx >> 5, j = idx & 31;
  float invf = (float)exp((double)(2 * j) * -0.14391156847064293);
  float ang = (float)s * invf;
  float sn, cs;
  sincosf(ang, &sn, &cs);
  tab[idx] = cs;
  tab[65536 + idx] = sn;
}

// ---------------------------------------------------------------------------
// init: xb = bf16(tokens), sumsq_a[row] = sum(tokens_row^2). 4 rows/block.
// ---------------------------------------------------------------------------
__global__ __launch_bounds__(256)
void init_kernel(const float* __restrict__ tok, bf16* __restrict__ xb,
                 float* __restrict__ sumsq)
{
  int row = blockIdx.x * 4 + (threadIdx.x >> 6);
  int lane = threadIdx.x & 63;
  const float* p = tok + (size_t)row * 512;
  float4 v0 = *(const float4*)(p + lane * 4);
  float4 v1 = *(const float4*)(p + 256 + lane * 4);
  float ss = v0.x*v0.x + v0.y*v0.y + v0.z*v0.z + v0.w*v0.w
           + v1.x*v1.x + v1.y*v1.y + v1.z*v1.z + v1.w*v1.w;
  #pragma unroll
  for (int d = 1; d < 64; d <<= 1) ss += __shfl_xor(ss, d);
  float a0[4] = {v0.x, v0.y, v0.z, v0.w};
  float a1[4] = {v1.x, v1.y, v1.z, v1.w};
  #pragma unroll
  for (int i = 0; i < 4; ++i) {
    xb[(size_t)row * 512 + lane * 4 + i]       = (bf16)a0[i];
    xb[(size_t)row * 512 + 256 + lane * 4 + i] = (bf16)a1[i];
  }
  if (lane == 0) sumsq[row] = ss;
}

// ---------------------------------------------------------------------------
// Final RMSNorm: fp32 out. One wave per row, 4 rows/block.
// ---------------------------------------------------------------------------
__global__ __launch_bounds__(256)
void rmsnorm_kernel(const float* __restrict__ in, const float* __restrict__ wgt,
                    float* __restrict__ outp)
{
  int row = blockIdx.x * 4 + (threadIdx.x >> 6);
  int lane = threadIdx.x & 63;
  const float* p = in + (size_t)row * 512;
  float4 v0 = *(const float4*)(p + lane * 4);
  float4 v1 = *(const float4*)(p + 256 + lane * 4);
  float ss = v0.x*v0.x + v0.y*v0.y + v0.z*v0.z + v0.w*v0.w
           + v1.x*v1.x + v1.y*v1.y + v1.z*v1.z + v1.w*v1.w;
  #pragma unroll
  for (int d = 1; d < 64; d <<= 1) ss += __shfl_xor(ss, d);
  float sc = rsqrtf(ss * (1.f / 512.f) + 1.1920929e-7f);
  float a0[4] = {v0.x, v0.y, v0.z, v0.w};
  float a1[4] = {v1.x, v1.y, v1.z, v1.w};
  #pragma unroll
  for (int i = 0; i < 4; ++i) {
    int c0 = lane * 4 + i, c1 = 256 + lane * 4 + i;
    outp[(size_t)row * 512 + c0] = a0[i] * sc * wgt[c0];
    outp[(size_t)row * 512 + c1] = a1[i] * sc * wgt[c1];
  }
}

// ---------------------------------------------------------------------------
// qkv post with LDS transpose for vT. grid (st=32, bh=16), 256 threads.
// ---------------------------------------------------------------------------
__global__ __launch_bounds__(256, 4)
void qkvpost_kernel(const bf16* __restrict__ qkv, const float* __restrict__ mb,
                    const float* __restrict__ rope, bf16* __restrict__ firstv,
                    bf16* __restrict__ qb, bf16* __restrict__ kb,
                    bf16* __restrict__ vT, int layer)
{
  __shared__ float smv[64][65];
  const int st = blockIdx.x, bh = blockIdx.y;
  const int b = bh >> 3, h = bh & 7;
  const int tid = threadIdx.x;
  const int sl = tid >> 2, dg = tid & 3;
  const int s = st * 64 + sl;
  const size_t row = (size_t)b * 2048 + s;
  const bf16* base = qkv + row * 1664 + h * 64 + dg * 16;

  bf16x8 qv0 = *(const bf16x8*)(base);
  bf16x8 qv1 = *(const bf16x8*)(base + 8);
  bf16x8 kv0 = *(const bf16x8*)(base + 512);
  bf16x8 kv1 = *(const bf16x8*)(base + 520);
  bf16x8 vv0 = *(const bf16x8*)(base + 1024);
  bf16x8 vv1 = *(const bf16x8*)(base + 1032);

  float cs8[8], sn8[8];
  #pragma unroll
  for (int j = 0; j < 8; ++j) {
    cs8[j] = rope[s * 32 + dg * 8 + j];
    sn8[j] = rope[65536 + s * 32 + dg * 8 + j];
  }

  const size_t qoff = ((size_t)bh * 2048 + s) * 64 + dg * 16;
  bf16x8 oq0, oq1, ok0, ok1;
  #pragma unroll
  for (int p = 0; p < 4; ++p) {
    float q1 = (float)qv0[2 * p], q2 = (float)qv0[2 * p + 1];
    float k1 = (float)kv0[2 * p], k2 = (float)kv0[2 * p + 1];
    oq0[2 * p]     = (bf16)((q1 * cs8[p] - q2 * sn8[p]) * 0.125f);
    oq0[2 * p + 1] = (bf16)((q1 * sn8[p] + q2 * cs8[p]) * 0.125f);
    ok0[2 * p]     = (bf16)(k1 * cs8[p] - k2 * sn8[p]);
    ok0[2 * p + 1] = (bf16)(k1 * sn8[p] + k2 * cs8[p]);
    float q3 = (float)qv1[2 * p], q4v = (float)qv1[2 * p + 1];
    float k3 = (float)kv1[2 * p], k4 = (float)kv1[2 * p + 1];
    oq1[2 * p]     = (bf16)((q3 * cs8[p + 4] - q4v * sn8[p + 4]) * 0.125f);
    oq1[2 * p + 1] = (bf16)((q3 * sn8[p + 4] + q4v * cs8[p + 4]) * 0.125f);
    ok1[2 * p]     = (bf16)(k3 * cs8[p + 4] - k4 * sn8[p + 4]);
    ok1[2 * p + 1] = (bf16)(k3 * sn8[p + 4] + k4 * cs8[p + 4]);
  }
  *(bf16x8*)(qb + qoff)     = oq0;
  *(bf16x8*)(qb + qoff + 8) = oq1;
  *(bf16x8*)(kb + qoff)     = ok0;
  *(bf16x8*)(kb + qoff + 8) = ok1;

  float vout[16];
  #pragma unroll
  for (int i = 0; i < 8; ++i) { vout[i] = (float)vv0[i]; vout[8 + i] = (float)vv1[i]; }
  if (layer == 0) {
    *(bf16x8*)(firstv + qoff)     = vv0;
    *(bf16x8*)(firstv + qoff + 8) = vv1;
  } else {
    float logit = (float)qkv[row * 1664 + 1536 + h] + mb[h];
    float mx = 1.f / (1.f + __expf(-logit));
    bf16x8 fv0 = *(const bf16x8*)(firstv + qoff);
    bf16x8 fv1 = *(const bf16x8*)(firstv + qoff + 8);
    #pragma unroll
    for (int i = 0; i < 8; ++i) {
      vout[i]     += mx * ((float)fv0[i] - vout[i]);
      vout[8 + i] += mx * ((float)fv1[i] - vout[8 + i]);
    }
  }
  #pragma unroll
  for (int i = 0; i < 16; ++i)
    smv[sl][dg * 16 + i] = vout[i];

  __syncthreads();

  const int d = tid >> 2, q4 = tid & 3;
  bf16x8 o0, o1;
  #pragma unroll
  for (int i = 0; i < 8; ++i) {
    o0[i] = (bf16)smv[q4 * 16 + i][d];
    o1[i] = (bf16)smv[q4 * 16 + 8 + i][d];
  }
  bf16* vp = vT + ((size_t)bh * 64 + d) * 2048 + st * 64 + q4 * 16;
  *(bf16x8*)(vp)     = o0;
  *(bf16x8*)(vp + 8) = o1;
}

// ---------------------------------------------------------------------------
// Split-K flash attention (r8 structure: double-buffer + __syncthreads,
// 3 blocks/CU). 128 q-rows/block, block-causal (block 32). 640 blocks.
// Fixed-max softmax; bf16 O-partials.
// ---------------------------------------------------------------------------
__global__ __launch_bounds__(256, 3)
void attn_kernel(const bf16* __restrict__ Q, const bf16* __restrict__ Kmat,
                 const bf16* __restrict__ VT, bf16* __restrict__ Opart,
                 float* __restrict__ lbuf)
{
  __shared__ __align__(16) bf16 smK[2][8 * 512];
  __shared__ __align__(16) bf16 smV[2][8 * 512];
  __shared__ __align__(16) bf16 smP[4][2][16 * 72];
  const int bid = blockIdx.x;
  const int bh = bid & 15;
  const int cidx = bid >> 4;
  int qtp, chunk;
  if (cidx < 4)       { qtp = cidx; chunk = 0; }
  else if (cidx < 12) { qtp = 4 + ((cidx - 4) >> 1);  chunk = (cidx - 4) & 1; }
  else if (cidx < 24) { int t = cidx - 12; qtp = 8 + t / 3; chunk = t - (qtp - 8) * 3; }
  else                { int t = cidx - 24; qtp = 12 + (t >> 2); chunk = t & 3; }
  const int jt0 = chunk * 8;
  const int njt = min(jt0 + 8, 2 * qtp + 2) - jt0;

  const int tid = threadIdx.x;
  const int w = tid >> 6, lane = tid & 63;
  const int c = lane & 15, quad = lane >> 4;
  const int jtmax_w = (qtp * 4 + w) >> 1;

  const size_t qrow0 = (size_t)bh * 2048 + qtp * 128 + w * 32;
  bf16x8 aQ[2][2];
  #pragma unroll
  for (int m = 0; m < 2; ++m) {
    aQ[m][0] = *(const bf16x8*)(Q + (qrow0 + m * 16 + c) * 64 + quad * 8);
    aQ[m][1] = *(const bf16x8*)(Q + (qrow0 + m * 16 + c) * 64 + 32 + quad * 8);
  }

  const bf16* Kg = Kmat + ((size_t)bh * 2048 + w * 16 + c) * 64 + quad * 8;
  const bf16* Vg = VT + ((size_t)bh * 64 + w * 16 + c) * 2048 + quad * 8;

  {
    const bf16* kp = Kg + (size_t)jt0 * 4096;
    const bf16* vp = Vg + jt0 * 64;
    LDS16(kp,      smK[0] + w * 1024);
    LDS16(kp + 32, smK[0] + w * 1024 + 512);
    LDS16(vp,      smV[0] + w * 1024);
    LDS16(vp + 32, smV[0] + w * 1024 + 512);
  }

  f32x4 o[2][4] = {};
  float lacc[2][4] = {};

  for (int j = 0; j < njt; ++j) {
    const int b = j & 1;
    const int jt = jt0 + j;
    __syncthreads();
    if (j + 1 < njt) {
      const bf16* kp = Kg + (size_t)(jt + 1) * 4096;
      const bf16* vp = Vg + (jt + 1) * 64;
      bf16* kd = smK[1 - b] + w * 1024;
      bf16* vd = smV[1 - b] + w * 1024;
      LDS16(kp,      kd);
      LDS16(kp + 32, kd + 512);
      LDS16(vp,      vd);
      LDS16(vp + 32, vd + 512);
    }
    if (jt > jtmax_w) continue;

    f32x4 s[2][4];
    #pragma unroll
    for (int nt = 0; nt < 4; ++nt) {
      bf16x8 bK0 = *(const bf16x8*)(smK[b] + (nt * 2) * 512 + lane * 8);
      bf16x8 bK1 = *(const bf16x8*)(smK[b] + (nt * 2 + 1) * 512 + lane * 8);
      #pragma unroll
      for (int m = 0; m < 2; ++m) {
        f32x4 acc = {0.f, 0.f, 0.f, 0.f};
        acc = __builtin_amdgcn_mfma_f32_16x16x32_bf16(aQ[m][0], bK0, acc, 0, 0, 0);
        acc = __builtin_amdgcn_mfma_f32_16x16x32_bf16(aQ[m][1], bK1, acc, 0, 0, 0);
        s[m][nt] = acc;
      }
    }
    if (2 * jt + 1 > 4 * qtp + w) {
      #pragma unroll
      for (int m = 0; m < 2; ++m)
        #pragma unroll
        for (int r = 0; r < 4; ++r) { s[m][2][r] = -3.0e38f; s[m][3][r] = -3.0e38f; }
    }

    #pragma unroll
    for (int m = 0; m < 2; ++m) {
      #pragma unroll
      for (int r = 0; r < 4; ++r) {
        float p0 = __expf(s[m][0][r]);
        float p1 = __expf(s[m][1][r]);
        float p2 = __expf(s[m][2][r]);
        float p3 = __expf(s[m][3][r]);
        lacc[m][r] += (p0 + p1) + (p2 + p3);
        bf16* pp = smP[w][m] + (quad * 4 + r) * 72 + c;
        pp[0]  = (bf16)p0;
        pp[16] = (bf16)p1;
        pp[32] = (bf16)p2;
        pp[48] = (bf16)p3;
      }
    }
    asm volatile("s_waitcnt lgkmcnt(0)" ::: "memory");

    #pragma unroll
    for (int ks2 = 0; ks2 < 2; ++ks2) {
      #pragma unroll
      for (int m = 0; m < 2; ++m) {
        bf16x8 aP = *(const bf16x8*)(smP[w][m] + c * 72 + ks2 * 32 + quad * 8);
        #pragma unroll
        for (int nt = 0; nt < 4; ++nt) {
          bf16x8 bV = *(const bf16x8*)(smV[b] + (nt * 2 + ks2) * 512 + lane * 8);
          o[m][nt] = __builtin_amdgcn_mfma_f32_16x16x32_bf16(aP, bV, o[m][nt], 0, 0, 0);
        }
      }
    }
  }

  #pragma unroll
  for (int m = 0; m < 2; ++m)
    #pragma unroll
    for (int r = 0; r < 4; ++r) {
      float v = lacc[m][r];
      #pragma unroll
      for (int d = 1; d < 16; d <<= 1) v += __shfl_xor(v, d);
      lacc[m][r] = v;
    }

  const int slot = bh * 40 + cumoff2(qtp) + chunk;
  bf16* Op = Opart + (size_t)slot * 8192;
  #pragma unroll
  for (int m = 0; m < 2; ++m) {
    #pragma unroll
    for (int r = 0; r < 4; ++r) {
      int prow = w * 32 + m * 16 + quad * 4 + r;
      #pragma unroll
      for (int nt = 0; nt < 4; ++nt)
        Op[prow * 64 + nt * 16 + c] = (bf16)o[m][nt][r];
      if (c == 0) lbuf[slot * 128 + prow] = lacc[m][r];
    }
  }
}

// ---------------------------------------------------------------------------
// Combine split-K partials (bf16) -> bf16 O [b][s][512]. grid (32,16), 256 thr.
// ---------------------------------------------------------------------------
__global__ __launch_bounds__(256)
void attn_combine_kernel(const bf16* __restrict__ Opart, const float* __restrict__ lbuf,
                         bf16* __restrict__ Omat)
{
  const int qt = blockIdx.x, bh = blockIdx.y;
  const int qtp = qt >> 1;
  const int nch = (2 * qtp + 9) >> 3;
  const int base = bh * 40 + cumoff2(qtp);
  const int tid = threadIdx.x;
  const int row = tid >> 2, cg = tid & 3;
  const int prow = (qt & 1) * 64 + row;

  float L = 0.f;
  float acc[16] = {};
  #pragma unroll
  for (int ch = 0; ch < 4; ++ch) {
    if (ch < nch) {
      L += lbuf[(base + ch) * 128 + prow];
      const bf16* p = Opart + (size_t)(base + ch) * 8192 + prow * 64 + cg * 16;
      bf16x8 u0 = *(const bf16x8*)(p);
      bf16x8 u1 = *(const bf16x8*)(p + 8);
      #pragma unroll
      for (int i = 0; i < 8; ++i) { acc[i] += (float)u0[i]; acc[8 + i] += (float)u1[i]; }
    }
  }
  float inv = 1.f / L;

  const int b = bh >> 3, h = bh & 7;
  bf16* op = Omat + ((size_t)b * 2048 + qt * 64 + row) * 512 + h * 64 + cg * 16;
  #pragma unroll
  for (int i = 0; i < 16; ++i)
    op[i] = (bf16)(acc[i] * inv);
}

// ---------------------------------------------------------------------------
// GEMM 128x128 with folded-rmsnorm input scaling.
// MODE 0 (qkv): out bf16 = acc * sc[row]; block(0,0) zeros zbuf.
// MODE 3 (ffin gated-gelu): v = acc*sc[row] + bias[col]; pair via shfl;
//   out bf16 [M][N/2]; block(0,0) zeros zbuf.
// sc[row] = rsqrt(sumsq[row]/512 + eps).
// ---------------------------------------------------------------------------
template<int MODE>
__global__ __launch_bounds__(256, 2)
void gemm_kernel(const bf16* __restrict__ A, const bf16* __restrict__ WT,
                 const float* __restrict__ bias, const float* __restrict__ sumsq,
                 float* __restrict__ zbuf, void* __restrict__ outp,
                 int K, int N)
{
  __shared__ __align__(16) bf16 smA[8 * 512];
  __shared__ __align__(16) bf16 smB[8 * 512];
  const int tid = threadIdx.x;
  if (blockIdx.x == 0 && blockIdx.y == 0) {
    for (int i = tid; i < 4096; i += 256) zbuf[i] = 0.f;
  }
  const int w = tid >> 6, lane = tid & 63;
  const int c = lane & 15, quad = lane >> 4;
  const int wy = w >> 1, wx = w & 1;
  const int bm = blockIdx.y * 128, bn = blockIdx.x * 128;

  f32x4 acc[4][4] = {};

  const bf16* Ag0 = A  + (size_t)(bm + (w * 2)     * 16 + c) * K + quad * 8;
  const bf16* Ag1 = A  + (size_t)(bm + (w * 2 + 1) * 16 + c) * K + quad * 8;
  const bf16* Bg0 = WT + (size_t)(bn + (w * 2)     * 16 + c) * K + quad * 8;
  const bf16* Bg1 = WT + (size_t)(bn + (w * 2 + 1) * 16 + c) * K + quad * 8;
  bf16* la0 = smA + (w * 2) * 512;
  bf16* la1 = smA + (w * 2 + 1) * 512;
  bf16* lb0 = smB + (w * 2) * 512;
  bf16* lb1 = smB + (w * 2 + 1) * 512;

  const int NK = K >> 5;
  for (int kk = 0; kk < NK; ++kk) {
    const int ko = kk * 32;
    LDS16(Ag0 + ko, la0);
    LDS16(Ag1 + ko, la1);
    LDS16(Bg0 + ko, lb0);
    LDS16(Bg1 + ko, lb1);
    __syncthreads();
    bf16x8 af[4], bfr[4];
    #pragma unroll
    for (int mt = 0; mt < 4; ++mt)
      af[mt] = *(const bf16x8*)(smA + (wy * 4 + mt) * 512 + lane * 8);
    #pragma unroll
    for (int nt = 0; nt < 4; ++nt)
      bfr[nt] = *(const bf16x8*)(smB + (wx * 4 + nt) * 512 + lane * 8);
    #pragma unroll
    for (int mt = 0; mt < 4; ++mt)
      #pragma unroll
      for (int nt = 0; nt < 4; ++nt)
        acc[mt][nt] = __builtin_amdgcn_mfma_f32_16x16x32_bf16(af[mt], bfr[nt], acc[mt][nt], 0, 0, 0);
    __syncthreads();
  }

  const int r0 = bm + wy * 64;
  const int c0 = bn + wx * 64;
  #pragma unroll
  for (int mt = 0; mt < 4; ++mt) {
    #pragma unroll
    for (int r = 0; r < 4; ++r) {
      size_t row = (size_t)(r0 + mt * 16 + quad * 4 + r);
      float sc = rsqrtf(sumsq[row] * (1.f / 512.f) + 1.1920929e-7f);
      #pragma unroll
      for (int nt = 0; nt < 4; ++nt) {
        int col = c0 + nt * 16 + c;
        float v = acc[mt][nt][r] * sc;
        if (MODE == 3) {
          v += bias[col];
          float g = __shfl_xor(v, 1);
          if ((c & 1) == 0) {
            float outv = v * 0.5f * g * (1.f + erff(g * 0.70710678118654752f));
            ((bf16*)outp)[row * (size_t)(N >> 1) + (col >> 1)] = (bf16)outv;
          }
        } else {
          ((bf16*)outp)[row * N + col] = (bf16)v;
        }
      }
    }
  }
}

// ---------------------------------------------------------------------------
// GEMM 64x64 residual epilogue: outf = Tin + acc + bias (fp32), also write
// bf16 copy and atomically accumulate per-row sumsq. N = 512.
// ---------------------------------------------------------------------------
__global__ __launch_bounds__(256, 4)
void gemm64_kernel(const bf16* __restrict__ A, const bf16* __restrict__ WT,
                   const float* __restrict__ bias, const float* __restrict__ Tin,
                   float* __restrict__ outf, bf16* __restrict__ bcopy,
                   float* __restrict__ sumsq, int K)
{
  __shared__ __align__(16) bf16 smA[4 * 512];
  __shared__ __align__(16) bf16 smB[4 * 512];
  const int tid = threadIdx.x;
  const int w = tid >> 6, lane = tid & 63;
  const int c = lane & 15, quad = lane >> 4;
  const int wy = w >> 1, wx = w & 1;
  const int bm = blockIdx.y * 64, bn = blockIdx.x * 64;

  f32x4 acc[2][2] = {};

  const bf16* Ag = A  + (size_t)(bm + w * 16 + c) * K + quad * 8;
  const bf16* Bg = WT + (size_t)(bn + w * 16 + c) * K + quad * 8;
  bf16* la = smA + w * 512;
  bf16* lb = smB + w * 512;

  const int NK = K >> 5;
  for (int kk = 0; kk < NK; ++kk) {
    const int ko = kk * 32;
    LDS16(Ag + ko, la);
    LDS16(Bg + ko, lb);
    __syncthreads();
    bf16x8 af[2], bfr[2];
    #pragma unroll
    for (int mt = 0; mt < 2; ++mt)
      af[mt] = *(const bf16x8*)(smA + (wy * 2 + mt) * 512 + lane * 8);
    #pragma unroll
    for (int nt = 0; nt < 2; ++nt)
      bfr[nt] = *(const bf16x8*)(smB + (wx * 2 + nt) * 512 + lane * 8);
    #pragma unroll
    for (int mt = 0; mt < 2; ++mt)
      #pragma unroll
      for (int nt = 0; nt < 2; ++nt)
        acc[mt][nt] = __builtin_amdgcn_mfma_f32_16x16x32_bf16(af[mt], bfr[nt], acc[mt][nt], 0, 0, 0);
    __syncthreads();
  }

  const int r0 = bm + wy * 32;
  const int c0 = bn + wx * 32;
  float ssq[2][4] = {};
  #pragma unroll
  for (int mt = 0; mt < 2; ++mt) {
    #pragma unroll
    for (int nt = 0; nt < 2; ++nt) {
      #pragma unroll
      for (int r = 0; r < 4; ++r) {
        size_t row = (size_t)(r0 + mt * 16 + quad * 4 + r);
        int col = c0 + nt * 16 + c;
        float bv = (bias != nullptr) ? bias[col] : 0.f;
        float v = Tin[row * 512 + col] + acc[mt][nt][r] + bv;
        outf[row * 512 + col] = v;
        bcopy[row * 512 + col] = (bf16)v;
        ssq[mt][r] += v * v;
      }
    }
  }
  #pragma unroll
  for (int mt = 0; mt < 2; ++mt)
    #pragma unroll
    for (int r = 0; r < 4; ++r) {
      float v = ssq[mt][r];
      #pragma unroll
      for (int d = 1; d < 16; d <<= 1) v += __shfl_xor(v, d);
      if (c == 0)
        atomicAdd(&sumsq[r0 + mt * 16 + quad * 4 + r], v);
    }
}

// ---------------------------------------------------------------------------
extern "C" void kernel_launch(void* const* d_in, const int* in_sizes, int n_in,
                              void* d_out, int out_size, void* d_ws, size_t ws_size,
                              hipStream_t stream)
{
  const float* tokens  = (const float*)d_in[0];
  const float* anw     = (const float*)d_in[1];
  const float* qkvw    = (const float*)d_in[2];
  const float* outw    = (const float*)d_in[3];
  const float* mixw    = (const float*)d_in[4];
  const float* mixbias = (const float*)d_in[5];
  const float* fnw     = (const float*)d_in[6];
  const float* ffiw    = (const float*)d_in[7];
  const float* ffib    = (const float*)d_in[8];
  const float* ffow    = (const float*)d_in[9];
  const float* ffob    = (const float*)d_in[10];
  const float* finw    = (const float*)d_in[11];
  float* outp = (float*)d_out;

  char* ws = (char*)d_ws;
  size_t off = 0;
  auto alloc = [&](size_t bytes) -> char* {
    char* p = ws + off;
    off += (bytes + 255) & ~(size_t)255;
    return p;
  };
  bf16* wtq    = (bf16*)alloc((size_t)4 * 1664 * 512 * 2);   // anw-folded qkv + mix
  bf16* wto    = (bf16*)alloc((size_t)4 * 512 * 512 * 2);
  bf16* wtfi   = (bf16*)alloc((size_t)4 * 2816 * 512 * 2);   // fnw-folded, a/g interleaved
  bf16* wtfo   = (bf16*)alloc((size_t)4 * 512 * 1408 * 2);
  float* ibias = (float*)alloc((size_t)4 * 2816 * 4);
  float* tbuf  = (float*)alloc((size_t)4096 * 512 * 4);
  bf16* xb     = (bf16*)alloc((size_t)4096 * 512 * 2);
  bf16* yb     = (bf16*)alloc((size_t)4096 * 512 * 2);
  char* qkvraw = alloc((size_t)4096 * 1664 * 2);           // bf16 qkv / bf16 Opart alias
  bf16* fv     = (bf16*)alloc((size_t)16 * 2048 * 64 * 2);
  bf16* qb     = (bf16*)alloc((size_t)16 * 2048 * 64 * 2);
  bf16* kbuf   = (bf16*)alloc((size_t)16 * 2048 * 64 * 2);
  bf16* vT     = (bf16*)alloc((size_t)16 * 2048 * 64 * 2);
  bf16* ob     = (bf16*)alloc((size_t)4096 * 512 * 2);
  bf16* actb   = (bf16*)alloc((size_t)4096 * 1408 * 2);
  float* rope  = (float*)alloc((size_t)2 * 65536 * 4);
  float* lbuf  = (float*)alloc((size_t)640 * 128 * 4);
  float* ssqa  = (float*)alloc((size_t)4096 * 4);
  float* ssqb  = (float*)alloc((size_t)4096 * 4);
  bf16* qkvbf  = (bf16*)qkvraw;
  bf16* Opart  = (bf16*)qkvraw;

  dim3 tcv(32, 8);
  convert_w_kernel<<<dim3(16, 48, 4), tcv, 0, stream>>>(
      qkvw, wtq, anw, 512, 1536, 512, 1536, (size_t)512 * 1536, (size_t)1664 * 512);
  convert_w_kernel<<<dim3(16, 4, 4), tcv, 0, stream>>>(
      mixw, wtq + (size_t)1536 * 512, anw, 512, 8, 512, 128, (size_t)512 * 8, (size_t)1664 * 512);
  convert_w_kernel<<<dim3(16, 16, 4), tcv, 0, stream>>>(
      outw, wto, nullptr, 512, 512, 512, 512, (size_t)512 * 512, (size_t)512 * 512);
  convert_w_ffin_kernel<<<dim3(16, 88, 4), tcv, 0, stream>>>(ffiw, wtfi, fnw);
  convert_w_kernel<<<dim3(44, 16, 4), tcv, 0, stream>>>(
      ffow, wtfo, nullptr, 1365, 512, 1408, 512, (size_t)1365 * 512, (size_t)1408 * 512);
  ibias_kernel<<<44, 256, 0, stream>>>(ffib, ibias);
  rope_kernel<<<256, 256, 0, stream>>>(rope);
  init_kernel<<<1024, 256, 0, stream>>>(tokens, xb, ssqa);

  for (int l = 0; l < 4; ++l) {
    // reads ssqa (attn-norm scale), zeros ssqb for the out-proj to fill
    gemm_kernel<0><<<dim3(13, 32), 256, 0, stream>>>(
        xb, wtq + (size_t)l * 1664 * 512, nullptr, ssqa, ssqb, qkvbf, 512, 1664);
    qkvpost_kernel<<<dim3(32, 16), 256, 0, stream>>>(
        qkvbf, mixbias + l * 8, rope, fv, qb, kbuf, vT, l);
    attn_kernel<<<640, 256, 0, stream>>>(qb, kbuf, vT, Opart, lbuf);
    attn_combine_kernel<<<dim3(32, 16), 256, 0, stream>>>(Opart, lbuf, ob);
    // t += o @ out_w; writes tbuf fp32 + yb bf16 + ssqb
    gemm64_kernel<<<dim3(8, 64), 256, 0, stream>>>(
        ob, wto + (size_t)l * 512 * 512, nullptr, (l == 0) ? tokens : tbuf,
        tbuf, yb, ssqb, 512);
    // reads ssqb (ff-norm scale), zeros ssqa for the ffo to fill
    gemm_kernel<3><<<dim3(22, 32), 256, 0, stream>>>(
        yb, wtfi + (size_t)l * 2816 * 512, ibias + (size_t)l * 2816, ssqb, ssqa, actb, 512, 2816);
    // t += act @ ffo_w + b; writes tbuf fp32 + xb bf16 + ssqa
    gemm64_kernel<<<dim3(8, 64), 256, 0, stream>>>(
        actb, wtfo + (size_t)l * 512 * 1408, ffob + (size_t)l * 512, tbuf,
        tbuf, xb, ssqa, 1408);
  }
  rmsnorm_kernel<<<1024, 256, 0, stream>>>(tbuf, finw, outp);
}